// Round 12
// baseline (211.927 us; speedup 1.0000x reference)
//
#include <hip/hip_runtime.h>
#include <hip/hip_bf16.h>

typedef __bf16 bf16_t;
typedef bf16_t bf16x8 __attribute__((ext_vector_type(8)));
typedef bf16_t bf16x4 __attribute__((ext_vector_type(4)));
typedef float f32x4 __attribute__((ext_vector_type(4)));

#define SEQ 4096
#define BSZ 32
#define T_TOK 64
#define PROWS 66          // panel rows: tokens t0-1 .. t0+64
#define LSTR 264          // row stride elems (528 B)
#define NPANEL (PROWS * LSTR)

// LDS: four 66x264 bf16 panels:
//   X0/X1 ping-pong: hbf(j) lives through P4 (residual); the other panel
//   holds S(j) after P3', then is overwritten with staged h(j+1) during P4.
//   A: A (P1a out) -> HN (P3' out);  B: B (P1a out)
#define OFF_X0 0
#define OFF_X1 NPANEL
#define OFF_A  (2 * NPANEL)
#define OFF_B  (3 * NPANEL)
#define SMEM_ELEMS (4 * NPANEL)
#define SMEM_BYTES (SMEM_ELEMS * 2)     // 139392 B -> 1 block/CU

// frag-linear weight bases (bf16 elems). Frag (nt,ks) = 512 elems;
// lane l (r=l&15,kg=l>>4), elem e -> W^T[nt*16+r][ks*32+kg*8+e]
#define W1F 0           // [w1a|w1b]: 32 nt
#define NAF 131072      // nw1a: 16 nt
#define WBF 196608      // W2B = ew2 @ nw1b: 16 nt
#define N2F 262144      // nw2: 16 nt
#define B2N 327680      // 256 f32: eb2 @ nw1b

#define BAR() asm volatile("s_waitcnt lgkmcnt(0)\n\ts_barrier" ::: "memory")

// ---- prepass 1: direct transposes -> frag-linear bf16 ----
__global__ void wprep(const float* __restrict__ ew1, const float* __restrict__ nw1,
                      const float* __restrict__ nw2, bf16_t* __restrict__ wsw) {
    int idx = blockIdx.x * 256 + threadIdx.x;      // 0..262143
    int region, rel, outbase;
    if (idx < 131072)      { region = 0; rel = idx;          outbase = W1F; }
    else if (idx < 196608) { region = 1; rel = idx - 131072; outbase = NAF; }
    else                   { region = 2; rel = idx - 196608; outbase = N2F; }
    int f = rel >> 9, o = rel & 511;
    int l = o >> 3, e = o & 7;
    int r = l & 15, kg = l >> 4;
    int nt = f >> 3, ks = f & 7;
    int k = ks * 32 + kg * 8 + e;
    int n = nt * 16 + r;
    float v;
    if (region == 0)
        v = (nt < 16) ? ew1[k * 256 + n] : ew1[(256 + k) * 256 + (n - 256)];
    else if (region == 1)
        v = nw1[k * 256 + n];
    else
        v = nw2[k * 256 + n];
    wsw[outbase + rel] = (bf16_t)v;
}

// ---- prepass 2: W2B = ew2 @ nw1b (frag-linear), b2n = eb2 @ nw1b ----
__global__ void wprep2(const float* __restrict__ ew2, const float* __restrict__ eb2,
                       const float* __restrict__ nw1, bf16_t* __restrict__ wsw) {
    int k = blockIdx.x;
    int n = threadIdx.x;
    if (k < 256) {
        float acc = 0.f;
        for (int j = 0; j < 256; ++j)
            acc += ew2[k * 256 + j] * nw1[(256 + j) * 256 + n];
        int ks = k >> 5, kg = (k >> 3) & 3, e = k & 7;
        int nt = n >> 4, r = n & 15;
        wsw[WBF + ((nt * 8 + ks) << 9) + ((kg * 16 + r) << 3) + e] = (bf16_t)acc;
    } else {
        float acc = 0.f;
        for (int j = 0; j < 256; ++j)
            acc += eb2[j] * nw1[(256 + j) * 256 + n];
        ((float*)(wsw + B2N))[n] = acc;
    }
}

// Register discipline (R7-R10 lessons): at 512 threads the allocator caps at
// 128 arch-VGPRs; demand must stay under it. P4 (the peak phase: holds
// weights + staging) uses a SINGLE activation buffer and ONE 8-reg staging
// chunk in flight. Other phases keep the fA/fB ping-pong (no staging there).
__launch_bounds__(512, 2)
__global__ void gnl_kernel(const float* __restrict__ h, const float* __restrict__ mask,
                           const float* __restrict__ eb1, const float* __restrict__ nb1,
                           const float* __restrict__ nb2,
                           const bf16_t* __restrict__ wsw, float* __restrict__ out) {
    extern __shared__ bf16_t sm[];

    const int tid   = threadIdx.x;
    const int lane  = tid & 63;
    const int w     = tid >> 6;            // wave 0..7
    const int batch = blockIdx.x >> 3;     // 8 blocks per batch row
    const int tcb   = (blockIdx.x & 7) * 8;  // first tile-col of this block
    const long baseTok = (long)batch * SEQ;

    const int c   = lane & 15;             // token col / weight row
    const int kg  = lane >> 4;
    const int crb = kg << 2;               // C feature base {0,4,8,12}
    const int n0a = w * 16;
    const int n0b = (w + 8) * 16;

    auto loadw = [&](bf16x8 (&f)[8], const bf16_t* wp, int base, int nt) {
#pragma unroll
        for (int ks = 0; ks < 8; ++ks)
            f[ks] = *(const bf16x8*)(wp + base + ((nt * 8 + ks) << 9) + (lane << 3));
    };
    auto loada = [&](bf16x8 (&f)[8], int poff, int rbase) {
        const bf16_t* p = sm + poff + (rbase + c) * LSTR + (kg << 3);
#pragma unroll
        for (int ks = 0; ks < 8; ++ks) f[ks] = *(const bf16x8*)(p + (ks << 5));
    };
    auto mfma2 = [&](bf16x8 (&f)[8], bf16x8 (&wa)[8], bf16x8 (&wb)[8],
                     f32x4& a0, f32x4& a1) {
        __builtin_amdgcn_s_setprio(1);
#pragma unroll
        for (int ks = 0; ks < 8; ++ks) {
            a0 = __builtin_amdgcn_mfma_f32_16x16x32_bf16(wa[ks], f[ks], a0, 0, 0, 0);
            a1 = __builtin_amdgcn_mfma_f32_16x16x32_bf16(wb[ks], f[ks], a1, 0, 0, 0);
        }
        __builtin_amdgcn_s_setprio(0);
    };

    // ---------- prologue: stage tile 0 -> X0 ----------
    {
        const int t00 = tcb * T_TOK;
#pragma unroll
        for (int k = 0; k < 5; ++k) {
            int cc = tid + k * 512;
            if (cc < PROWS * 32) {
                int r = cc >> 5, fc = (cc & 31) << 3;
                int t = t00 - 1 + r;
                bf16x8 v;
                if (t >= 0 && t < SEQ) {
                    const float* src = h + (((long)(baseTok + t)) << 8) + fc;
                    float4 x0 = ((const float4*)src)[0];
                    float4 x1 = ((const float4*)src)[1];
                    v[0] = (bf16_t)x0.x; v[1] = (bf16_t)x0.y;
                    v[2] = (bf16_t)x0.z; v[3] = (bf16_t)x0.w;
                    v[4] = (bf16_t)x1.x; v[5] = (bf16_t)x1.y;
                    v[6] = (bf16_t)x1.z; v[7] = (bf16_t)x1.w;
                } else {
#pragma unroll
                    for (int q = 0; q < 8; ++q) v[q] = (bf16_t)0.0f;
                }
                *(bf16x8*)(sm + OFF_X0 + r * LSTR + fc) = v;
            }
        }
    }
    BAR();

    // ---------- tile loop ----------
    for (int j = 0; j < 8; ++j) {
        const bf16_t* wsw_ = wsw;
        asm volatile("" : "+s"(wsw_));     // opaque copy: blocks LICM hoisting
        const int t0 = (tcb + j) * T_TOK;  //   of weight frags across tiles
        const int hb = (j & 1) ? OFF_X1 : OFF_X0;
        const int sp = (j & 1) ? OFF_X0 : OFF_X1;
        const int nt0 = (tcb + j + 1) * T_TOK;   // next tile base (j<7 only)

        // staging: chunk k covers cc = tid + k*512 (5 chunks, last partial)
        auto issue_chunk = [&](int k, float4& c0, float4& c1) {
            int cc = tid + k * 512;
            if (cc < PROWS * 32) {
                int r = cc >> 5, fc = (cc & 31) << 3;
                int t = nt0 - 1 + r;
                int tc = (t < 0) ? 0 : ((t > SEQ - 1) ? SEQ - 1 : t);
                const float* src = h + (((long)(baseTok + tc)) << 8) + fc;
                c0 = ((const float4*)src)[0];
                c1 = ((const float4*)src)[1];
            }
        };
        auto write_chunk = [&](int k, const float4& c0, const float4& c1) {
            int cc = tid + k * 512;
            if (cc < PROWS * 32) {
                int r = cc >> 5, fc = (cc & 31) << 3;
                int t = nt0 - 1 + r;
                bf16x8 v;
                if (t >= 0 && t < SEQ) {
                    v[0] = (bf16_t)c0.x; v[1] = (bf16_t)c0.y;
                    v[2] = (bf16_t)c0.z; v[3] = (bf16_t)c0.w;
                    v[4] = (bf16_t)c1.x; v[5] = (bf16_t)c1.y;
                    v[6] = (bf16_t)c1.z; v[7] = (bf16_t)c1.w;
                } else {
#pragma unroll
                    for (int q = 0; q < 8; ++q) v[q] = (bf16_t)0.0f;
                }
                *(bf16x8*)(sm + sp + r * LSTR + fc) = v;
            }
        };

        // ----- Phase 1a: A,B panels = hbf @ [w1a|w1b] -----
#pragma unroll
        for (int p = 0; p < 2; ++p) {
            bf16x8 wa[8], wb[8];
            loadw(wa, wsw_, W1F, w + p * 16);
            loadw(wb, wsw_, W1F, w + p * 16 + 8);
            int poff = p ? OFF_B : OFF_A;
            bf16x8 fA[8], fB[8];
            loada(fA, hb, 0);
#pragma unroll
            for (int mt = 0; mt < 5; ++mt) {
                bf16x8 (&cur)[8] = (mt & 1) ? fB : fA;
                bf16x8 (&nxt)[8] = (mt & 1) ? fA : fB;
                if (mt < 4) loada(nxt, hb, (mt + 1) * 16);
                f32x4 aA = {0.f, 0.f, 0.f, 0.f}, aB = {0.f, 0.f, 0.f, 0.f};
                mfma2(cur, wa, wb, aA, aB);
                int row = mt * 16 + c;
                if (row < PROWS) {
                    bf16x4 pA, pB;
#pragma unroll
                    for (int q = 0; q < 4; ++q) { pA[q] = (bf16_t)aA[q]; pB[q] = (bf16_t)aB[q]; }
                    *(bf16x4*)(sm + poff + row * LSTR + n0a + crb) = pA;
                    *(bf16x4*)(sm + poff + row * LSTR + n0b + crb) = pB;
                }
            }
        }

        // ----- Phase 1b: HA = h @ nw1a (f32 regs, consumed in P3') -----
        f32x4 ha[4][2];
        {
            bf16x8 na[8], nb8[8];
            loadw(na, wsw_, NAF, w);
            loadw(nb8, wsw_, NAF, w + 8);
            bf16x8 fA[8], fB[8];
            loada(fA, hb, 1);
#pragma unroll
            for (int tm = 0; tm < 4; ++tm) {
                bf16x8 (&cur)[8] = (tm & 1) ? fB : fA;
                bf16x8 (&nxt)[8] = (tm & 1) ? fA : fB;
                if (tm < 3) loada(nxt, hb, tm * 16 + 17);
                f32x4 a0 = {0.f, 0.f, 0.f, 0.f}, a1 = {0.f, 0.f, 0.f, 0.f};
                mfma2(cur, na, nb8, a0, a1);
                ha[tm][0] = a0; ha[tm][1] = a1;
            }
        }

        // prefetch P3' weights (W2B) — stay in flight across the barrier
        bf16x8 wba[8], wbb[8];
        loadw(wba, wsw_, WBF, w);
        loadw(wbb, wsw_, WBF, w + 8);
        BAR();

        // ----- S pass -> sp panel (rows = token index) -----
#pragma unroll
        for (int it = 0; it < 4; ++it) {
            int cc = tid + it * 512;           // 64*32 = 2048 exactly
            int i = cc >> 5;
            int fc = (cc & 31) << 3;
            float bl = (t0 + i >= 1) ? 1.f : 0.f;
            float br = (t0 + i <= SEQ - 2) ? 1.f : 0.f;
            bf16x8 aL = *(const bf16x8*)(sm + OFF_A + i * LSTR + fc);
            bf16x8 aR = *(const bf16x8*)(sm + OFF_A + (i + 2) * LSTR + fc);
            bf16x8 bC = *(const bf16x8*)(sm + OFF_B + (i + 1) * LSTR + fc);
            float4 b1a = *(const float4*)(eb1 + fc);
            float4 b1b = *(const float4*)(eb1 + fc + 4);
            bf16x8 sv;
#pragma unroll
            for (int q = 0; q < 8; ++q) {
                float b1f = (q < 4) ? ((const float*)&b1a)[q] : ((const float*)&b1b)[q - 4];
                float x = (float)bC[q] + b1f;
                float l = fmaxf((float)aL[q] + x, 0.f) * bl;
                float r = fmaxf((float)aR[q] + x, 0.f) * br;
                sv[q] = (bf16_t)(l + r);
            }
            *(bf16x8*)(sm + sp + i * LSTR + fc) = sv;
        }
        BAR();

        // ----- Phase 3': HN = relu(HA + S @ W2B + nb1 + cnt*b2n) -> A panel -----
        {
            float4 n1a = *(const float4*)(nb1 + n0a + crb);
            float4 n1b = *(const float4*)(nb1 + n0b + crb);
            const float* b2n = (const float*)(wsw_ + B2N);
            float4 c2a = *(const float4*)(b2n + n0a + crb);
            float4 c2b = *(const float4*)(b2n + n0b + crb);
            bf16x8 fA[8], fB[8];
            loada(fA, sp, 0);
#pragma unroll
            for (int tm = 0; tm < 4; ++tm) {
                bf16x8 (&cur)[8] = (tm & 1) ? fB : fA;
                bf16x8 (&nxt)[8] = (tm & 1) ? fA : fB;
                if (tm < 3) loada(nxt, sp, (tm + 1) * 16);
                f32x4 a0 = ha[tm][0], a1 = ha[tm][1];
                mfma2(cur, wba, wbb, a0, a1);
                int row = tm * 16 + c;
                int t = t0 + row;
                float cnt = ((t >= 1) ? 1.f : 0.f) + ((t <= SEQ - 2) ? 1.f : 0.f);
                bf16x4 p0, p1;
#pragma unroll
                for (int q = 0; q < 4; ++q) {
                    p0[q] = (bf16_t)fmaxf(a0[q] + ((const float*)&n1a)[q] + cnt * ((const float*)&c2a)[q], 0.f);
                    p1[q] = (bf16_t)fmaxf(a1[q] + ((const float*)&n1b)[q] + cnt * ((const float*)&c2b)[q], 0.f);
                }
                *(bf16x4*)(sm + OFF_A + row * LSTR + n0a + crb) = p0;
                *(bf16x4*)(sm + OFF_A + row * LSTR + n0b + crb) = p1;
            }
        }
        // prefetch P4 weights (nw2)
        bf16x8 n2a[8], n2b[8];
        loadw(n2a, wsw_, N2F, w);
        loadw(n2b, wsw_, N2F, w + 8);
        BAR();

        // ----- Phase 4: out = X + mask*(HN @ nw2 + nb2), staging interleaved -----
        // sp panel dead after P3' (barrier above) -> staged h(j+1) writes safe.
        // ONE chunk (8 regs) in flight: issued at iter end, written next iter.
        {
            float4 v2a = *(const float4*)(nb2 + n0a + crb);
            float4 v2b = *(const float4*)(nb2 + n0b + crb);
            float4 cc0, cc1;
            if (j < 7) issue_chunk(0, cc0, cc1);
            bf16x8 f[8];
#pragma unroll
            for (int tm = 0; tm < 4; ++tm) {
                loada(f, OFF_A, tm * 16);
                long t = baseTok + t0 + tm * 16 + c;
                float m = mask[t];
                f32x4 a0 = {0.f, 0.f, 0.f, 0.f}, a1 = {0.f, 0.f, 0.f, 0.f};
                mfma2(f, n2a, n2b, a0, a1);
                int rrow = tm * 16 + c + 1;           // X row of this token
                bf16x4 r0 = *(const bf16x4*)(sm + hb + rrow * LSTR + n0a + crb);
                bf16x4 r1 = *(const bf16x4*)(sm + hb + rrow * LSTR + n0b + crb);
                long g0 = (t << 8) + n0a + crb;
                long g1 = (t << 8) + n0b + crb;
                float4 o0, o1;
                o0.x = (float)r0[0] + m * (a0[0] + v2a.x);
                o0.y = (float)r0[1] + m * (a0[1] + v2a.y);
                o0.z = (float)r0[2] + m * (a0[2] + v2a.z);
                o0.w = (float)r0[3] + m * (a0[3] + v2a.w);
                o1.x = (float)r1[0] + m * (a1[0] + v2b.x);
                o1.y = (float)r1[1] + m * (a1[1] + v2b.y);
                o1.z = (float)r1[2] + m * (a1[2] + v2b.z);
                o1.w = (float)r1[3] + m * (a1[3] + v2b.w);
                *(float4*)(out + g0) = o0;
                *(float4*)(out + g1) = o1;
                if (j < 7) {
                    write_chunk(tm, cc0, cc1);        // chunk tm done
                    issue_chunk(tm + 1, cc0, cc1);    // chunk tm+1 in flight
                }
            }
            if (j < 7) write_chunk(4, cc0, cc1);      // partial tail chunk
        }
        BAR();
    }
}

extern "C" void kernel_launch(void* const* d_in, const int* in_sizes, int n_in,
                              void* d_out, int out_size, void* d_ws, size_t ws_size,
                              hipStream_t stream) {
    const float* h    = (const float*)d_in[0];
    const float* mask = (const float*)d_in[1];
    const float* ew1  = (const float*)d_in[2];
    const float* eb1  = (const float*)d_in[3];
    const float* ew2  = (const float*)d_in[4];
    const float* eb2  = (const float*)d_in[5];
    const float* nw1  = (const float*)d_in[6];
    const float* nb1  = (const float*)d_in[7];
    const float* nw2  = (const float*)d_in[8];
    const float* nb2  = (const float*)d_in[9];
    float* out   = (float*)d_out;
    bf16_t* wsw  = (bf16_t*)d_ws;

    wprep<<<1024, 256, 0, stream>>>(ew1, nw1, nw2, wsw);
    wprep2<<<257, 256, 0, stream>>>(ew2, eb2, nw1, wsw);

    hipFuncSetAttribute(reinterpret_cast<const void*>(gnl_kernel),
                        hipFuncAttributeMaxDynamicSharedMemorySize, SMEM_BYTES);

    gnl_kernel<<<256, 512, SMEM_BYTES, stream>>>(
        h, mask, eb1, nb1, nb2, wsw, out);
}

// Round 13
// 159.640 us; speedup vs baseline: 1.3275x; 1.3275x over previous
//
#include <hip/hip_runtime.h>
#include <hip/hip_bf16.h>

typedef __bf16 bf16_t;
typedef bf16_t bf16x8 __attribute__((ext_vector_type(8)));
typedef bf16_t bf16x4 __attribute__((ext_vector_type(4)));
typedef float f32x4 __attribute__((ext_vector_type(4)));

#define SEQ 4096
#define BSZ 32
#define T_TOK 48
#define TILES 86          // ceil(4096/48); last tile has 16 valid tokens
#define PROWS 50          // X panel rows: tokens t0-1 .. t0+48
#define LSTR 264          // row stride elems (528 B)
#define NPANEL (PROWS * LSTR)

// LDS: THREE 50x264 bf16 panels = 79200 B -> 2 blocks/CU (158.4 of 160 KiB).
//   X: h bf16, alive to P4 (residual).  A: P1a out -> HN (P3' out).
//   B: P1a out -> S (written after in-register S compute; B is dead then).
#define OFF_X 0
#define OFF_A NPANEL
#define OFF_B (2 * NPANEL)
#define SMEM_ELEMS (3 * NPANEL)
#define SMEM_BYTES (SMEM_ELEMS * 2)     // 79200

// frag-linear weight bases (bf16 elems). Frag (nt,ks) = 512 elems;
// lane l (r=l&15,kg=l>>4), elem e -> W^T[nt*16+r][ks*32+kg*8+e]
#define W1F 0           // [w1a|w1b]: 32 nt
#define NAF 131072      // nw1a: 16 nt
#define WBF 196608      // W2B = ew2 @ nw1b: 16 nt
#define N2F 262144      // nw2: 16 nt
#define B2N 327680      // 256 f32: eb2 @ nw1b

#define BAR() asm volatile("s_waitcnt lgkmcnt(0)\n\ts_barrier" ::: "memory")

// ---- prepass 1: direct transposes -> frag-linear bf16 ----
__global__ void wprep(const float* __restrict__ ew1, const float* __restrict__ nw1,
                      const float* __restrict__ nw2, bf16_t* __restrict__ wsw) {
    int idx = blockIdx.x * 256 + threadIdx.x;      // 0..262143
    int region, rel, outbase;
    if (idx < 131072)      { region = 0; rel = idx;          outbase = W1F; }
    else if (idx < 196608) { region = 1; rel = idx - 131072; outbase = NAF; }
    else                   { region = 2; rel = idx - 196608; outbase = N2F; }
    int f = rel >> 9, o = rel & 511;
    int l = o >> 3, e = o & 7;
    int r = l & 15, kg = l >> 4;
    int nt = f >> 3, ks = f & 7;
    int k = ks * 32 + kg * 8 + e;
    int n = nt * 16 + r;
    float v;
    if (region == 0)
        v = (nt < 16) ? ew1[k * 256 + n] : ew1[(256 + k) * 256 + (n - 256)];
    else if (region == 1)
        v = nw1[k * 256 + n];
    else
        v = nw2[k * 256 + n];
    wsw[outbase + rel] = (bf16_t)v;
}

// ---- prepass 2: W2B = ew2 @ nw1b (frag-linear), b2n = eb2 @ nw1b ----
__global__ void wprep2(const float* __restrict__ ew2, const float* __restrict__ eb2,
                       const float* __restrict__ nw1, bf16_t* __restrict__ wsw) {
    int k = blockIdx.x;
    int n = threadIdx.x;
    if (k < 256) {
        float acc = 0.f;
        for (int j = 0; j < 256; ++j)
            acc += ew2[k * 256 + j] * nw1[(256 + j) * 256 + n];
        int ks = k >> 5, kg = (k >> 3) & 3, e = k & 7;
        int nt = n >> 4, r = n & 15;
        wsw[WBF + ((nt * 8 + ks) << 9) + ((kg * 16 + r) << 3) + e] = (bf16_t)acc;
    } else {
        float acc = 0.f;
        for (int j = 0; j < 256; ++j)
            acc += eb2[j] * nw1[(256 + j) * 256 + n];
        ((float*)(wsw + B2N))[n] = acc;
    }
}

// Non-persistent (persistent failed 3x on the 128-VGPR pin). 512 threads,
// demand ~104 VGPR (proven clean). 79.2 KB LDS -> 2 blocks/CU: two
// independent barrier groups per CU hide each other's latency (m114).
__launch_bounds__(512, 2)
__global__ void gnl_kernel(const float* __restrict__ h, const float* __restrict__ mask,
                           const float* __restrict__ eb1, const float* __restrict__ nb1,
                           const float* __restrict__ nb2,
                           const bf16_t* __restrict__ wsw, float* __restrict__ out) {
    extern __shared__ bf16_t sm[];

    const int tid   = threadIdx.x;
    const int lane  = tid & 63;
    const int w     = tid >> 6;            // wave 0..7
    const int batch = blockIdx.x / TILES;
    const int tile  = blockIdx.x % TILES;
    const int t0    = tile * T_TOK;
    const long baseTok = (long)batch * SEQ;

    const int c   = lane & 15;             // token col / weight row
    const int kg  = lane >> 4;
    const int crb = kg << 2;               // C feature base {0,4,8,12}
    const int n0a = w * 16;
    const int n0b = (w + 8) * 16;

    auto loadw = [&](bf16x8 (&f)[8], int base, int nt) {
#pragma unroll
        for (int ks = 0; ks < 8; ++ks)
            f[ks] = *(const bf16x8*)(wsw + base + ((nt * 8 + ks) << 9) + (lane << 3));
    };
    auto loada = [&](bf16x8 (&f)[8], int poff, int rbase) {
        const bf16_t* p = sm + poff + (rbase + c) * LSTR + (kg << 3);
#pragma unroll
        for (int ks = 0; ks < 8; ++ks) f[ks] = *(const bf16x8*)(p + (ks << 5));
    };
    auto mfma2 = [&](bf16x8 (&f)[8], bf16x8 (&wa)[8], bf16x8 (&wb)[8],
                     f32x4& a0, f32x4& a1) {
        __builtin_amdgcn_s_setprio(1);
#pragma unroll
        for (int ks = 0; ks < 8; ++ks) {
            a0 = __builtin_amdgcn_mfma_f32_16x16x32_bf16(wa[ks], f[ks], a0, 0, 0, 0);
            a1 = __builtin_amdgcn_mfma_f32_16x16x32_bf16(wb[ks], f[ks], a1, 0, 0, 0);
        }
        __builtin_amdgcn_s_setprio(0);
    };

    // ---- prefetch P1a p=0 weight pair DURING stage (low-pressure region) ----
    bf16x8 wa0[8], wb0[8];
    loadw(wa0, W1F, w);
    loadw(wb0, W1F, w + 8);

    // ---------- stage h -> X (bf16, zero-padded boundary rows) ----------
#pragma unroll
    for (int it = 0; it < 4; ++it) {
        int cc = tid + it * 512;
        if (cc < PROWS * 32) {
            int r = cc >> 5;
            int fc = (cc & 31) << 3;
            int t = t0 - 1 + r;
            bf16x8 v;
            if (t >= 0 && t < SEQ) {
                const float* src = h + (((long)(baseTok + t)) << 8) + fc;
                float4 x0 = ((const float4*)src)[0];
                float4 x1 = ((const float4*)src)[1];
                v[0] = (bf16_t)x0.x; v[1] = (bf16_t)x0.y;
                v[2] = (bf16_t)x0.z; v[3] = (bf16_t)x0.w;
                v[4] = (bf16_t)x1.x; v[5] = (bf16_t)x1.y;
                v[6] = (bf16_t)x1.z; v[7] = (bf16_t)x1.w;
            } else {
#pragma unroll
                for (int q = 0; q < 8; ++q) v[q] = (bf16_t)0.0f;
            }
            *(bf16x8*)(sm + OFF_X + r * LSTR + fc) = v;
        }
    }
    BAR();

    // ---------- Phase 1a: A,B panels = X @ [w1a|w1b] ----------
    // 4 m-tiles cover rows 0..63 (valid 0..49; mt=3 reads spill benignly into
    // the A panel — outputs masked by row<PROWS).
#pragma unroll
    for (int p = 0; p < 2; ++p) {
        bf16x8 wa[8], wb[8];
        if (p == 0) {
#pragma unroll
            for (int ks = 0; ks < 8; ++ks) { wa[ks] = wa0[ks]; wb[ks] = wb0[ks]; }
        } else {
            loadw(wa, W1F, w + 16);
            loadw(wb, W1F, w + 24);
        }
        int poff = p ? OFF_B : OFF_A;
        bf16x8 fA[8], fB[8];
        loada(fA, OFF_X, 0);
#pragma unroll
        for (int mt = 0; mt < 4; ++mt) {
            bf16x8 (&cur)[8] = (mt & 1) ? fB : fA;
            bf16x8 (&nxt)[8] = (mt & 1) ? fA : fB;
            if (mt < 3) loada(nxt, OFF_X, (mt + 1) * 16);
            f32x4 aA = {0.f, 0.f, 0.f, 0.f}, aB = {0.f, 0.f, 0.f, 0.f};
            mfma2(cur, wa, wb, aA, aB);
            int row = mt * 16 + c;
            if (row < PROWS) {
                bf16x4 pA, pB;
#pragma unroll
                for (int q = 0; q < 4; ++q) { pA[q] = (bf16_t)aA[q]; pB[q] = (bf16_t)aB[q]; }
                *(bf16x4*)(sm + poff + row * LSTR + n0a + crb) = pA;
                *(bf16x4*)(sm + poff + row * LSTR + n0b + crb) = pB;
            }
        }
    }

    // ---------- Phase 1b: HA = h @ nw1a (f32 regs, consumed in P3') ----------
    f32x4 ha[3][2];
    {
        bf16x8 na[8], nb8[8];
        loadw(na, NAF, w);
        loadw(nb8, NAF, w + 8);
        bf16x8 fA[8], fB[8];
        loada(fA, OFF_X, 1);
#pragma unroll
        for (int tm = 0; tm < 3; ++tm) {
            bf16x8 (&cur)[8] = (tm & 1) ? fB : fA;
            bf16x8 (&nxt)[8] = (tm & 1) ? fA : fB;
            if (tm < 2) loada(nxt, OFF_X, tm * 16 + 17);
            f32x4 a0 = {0.f, 0.f, 0.f, 0.f}, a1 = {0.f, 0.f, 0.f, 0.f};
            mfma2(cur, na, nb8, a0, a1);
            ha[tm][0] = a0; ha[tm][1] = a1;
        }
    }

    // prefetch P3' weights (W2B) — stay in flight across the barrier
    bf16x8 wba[8], wbb[8];
    loadw(wba, WBF, w);
    loadw(wbb, WBF, w + 8);
    BAR();

    // ---------- S pass (register-held; S overwrites B panel) ----------
    // S[i] = bl*relu(A[i]+B[i+1]+b1) + br*relu(A[i+2]+B[i+1]+b1), i = 0..47.
    // Step 1: compute all 3 chunks into registers (reads A,B).
    bf16x8 svr[3];
#pragma unroll
    for (int it = 0; it < 3; ++it) {
        int cc = tid + it * 512;               // 48*32 = 1536 = 3*512 exact
        int i = cc >> 5;
        int fc = (cc & 31) << 3;
        float bl = (t0 + i >= 1) ? 1.f : 0.f;
        float br = (t0 + i <= SEQ - 2) ? 1.f : 0.f;
        bf16x8 aL = *(const bf16x8*)(sm + OFF_A + i * LSTR + fc);
        bf16x8 aR = *(const bf16x8*)(sm + OFF_A + (i + 2) * LSTR + fc);
        bf16x8 bC = *(const bf16x8*)(sm + OFF_B + (i + 1) * LSTR + fc);
        float4 b1a = *(const float4*)(eb1 + fc);
        float4 b1b = *(const float4*)(eb1 + fc + 4);
        bf16x8 sv;
#pragma unroll
        for (int q = 0; q < 8; ++q) {
            float b1f = (q < 4) ? ((const float*)&b1a)[q] : ((const float*)&b1b)[q - 4];
            float x = (float)bC[q] + b1f;
            float l = fmaxf((float)aL[q] + x, 0.f) * bl;
            float r = fmaxf((float)aR[q] + x, 0.f) * br;
            sv[q] = (bf16_t)(l + r);
        }
        svr[it] = sv;
    }
    BAR();   // all B reads done -> safe to overwrite B with S
    // Step 2: write S into B panel (row = token index).
#pragma unroll
    for (int it = 0; it < 3; ++it) {
        int cc = tid + it * 512;
        int i = cc >> 5;
        int fc = (cc & 31) << 3;
        *(bf16x8*)(sm + OFF_B + i * LSTR + fc) = svr[it];
    }
    BAR();

    // ---------- Phase 3': HN = relu(HA + S @ W2B + nb1 + cnt*b2n) -> A ----------
    {
        float4 n1a = *(const float4*)(nb1 + n0a + crb);
        float4 n1b = *(const float4*)(nb1 + n0b + crb);
        const float* b2n = (const float*)(wsw + B2N);
        float4 c2a = *(const float4*)(b2n + n0a + crb);
        float4 c2b = *(const float4*)(b2n + n0b + crb);
        bf16x8 fA[8], fB[8];
        loada(fA, OFF_B, 0);
#pragma unroll
        for (int tm = 0; tm < 3; ++tm) {
            bf16x8 (&cur)[8] = (tm & 1) ? fB : fA;
            bf16x8 (&nxt)[8] = (tm & 1) ? fA : fB;
            if (tm < 2) loada(nxt, OFF_B, (tm + 1) * 16);
            f32x4 a0 = ha[tm][0], a1 = ha[tm][1];
            mfma2(cur, wba, wbb, a0, a1);
            int row = tm * 16 + c;
            int t = t0 + row;
            float cnt = ((t >= 1) ? 1.f : 0.f) + ((t <= SEQ - 2) ? 1.f : 0.f);
            bf16x4 p0, p1;
#pragma unroll
            for (int q = 0; q < 4; ++q) {
                p0[q] = (bf16_t)fmaxf(a0[q] + ((const float*)&n1a)[q] + cnt * ((const float*)&c2a)[q], 0.f);
                p1[q] = (bf16_t)fmaxf(a1[q] + ((const float*)&n1b)[q] + cnt * ((const float*)&c2b)[q], 0.f);
            }
            *(bf16x4*)(sm + OFF_A + row * LSTR + n0a + crb) = p0;
            *(bf16x4*)(sm + OFF_A + row * LSTR + n0b + crb) = p1;
        }
    }
    // prefetch P4 weights (nw2)
    bf16x8 n2a[8], n2b[8];
    loadw(n2a, N2F, w);
    loadw(n2b, N2F, w + 8);
    BAR();

    // ---------- Phase 4: out = X + mask * (HN @ nw2 + nb2) ----------
    {
        float4 v2a = *(const float4*)(nb2 + n0a + crb);
        float4 v2b = *(const float4*)(nb2 + n0b + crb);
        bf16x8 fA[8], fB[8];
        loada(fA, OFF_A, 0);
#pragma unroll
        for (int tm = 0; tm < 3; ++tm) {
            int row = tm * 16 + c;
            int tok = t0 + row;                   // may exceed SEQ in last tile
            int tokc = (tok < SEQ) ? tok : (SEQ - 1);
            long t = baseTok + tokc;
            float m = mask[t];                    // clamped, in flight early
            bf16x8 (&cur)[8] = (tm & 1) ? fB : fA;
            bf16x8 (&nxt)[8] = (tm & 1) ? fA : fB;
            if (tm < 2) loada(nxt, OFF_A, (tm + 1) * 16);
            f32x4 a0 = {0.f, 0.f, 0.f, 0.f}, a1 = {0.f, 0.f, 0.f, 0.f};
            mfma2(cur, n2a, n2b, a0, a1);
            int rrow = row + 1;                   // X row of this token
            bf16x4 r0 = *(const bf16x4*)(sm + OFF_X + rrow * LSTR + n0a + crb);
            bf16x4 r1 = *(const bf16x4*)(sm + OFF_X + rrow * LSTR + n0b + crb);
            if (tok < SEQ) {
                long g0 = (t << 8) + n0a + crb;
                long g1 = (t << 8) + n0b + crb;
                float4 o0, o1;
                o0.x = (float)r0[0] + m * (a0[0] + v2a.x);
                o0.y = (float)r0[1] + m * (a0[1] + v2a.y);
                o0.z = (float)r0[2] + m * (a0[2] + v2a.z);
                o0.w = (float)r0[3] + m * (a0[3] + v2a.w);
                o1.x = (float)r1[0] + m * (a1[0] + v2b.x);
                o1.y = (float)r1[1] + m * (a1[1] + v2b.y);
                o1.z = (float)r1[2] + m * (a1[2] + v2b.z);
                o1.w = (float)r1[3] + m * (a1[3] + v2b.w);
                *(float4*)(out + g0) = o0;
                *(float4*)(out + g1) = o1;
            }
        }
    }
}

extern "C" void kernel_launch(void* const* d_in, const int* in_sizes, int n_in,
                              void* d_out, int out_size, void* d_ws, size_t ws_size,
                              hipStream_t stream) {
    const float* h    = (const float*)d_in[0];
    const float* mask = (const float*)d_in[1];
    const float* ew1  = (const float*)d_in[2];
    const float* eb1  = (const float*)d_in[3];
    const float* ew2  = (const float*)d_in[4];
    const float* eb2  = (const float*)d_in[5];
    const float* nw1  = (const float*)d_in[6];
    const float* nb1  = (const float*)d_in[7];
    const float* nw2  = (const float*)d_in[8];
    const float* nb2  = (const float*)d_in[9];
    float* out   = (float*)d_out;
    bf16_t* wsw  = (bf16_t*)d_ws;

    wprep<<<1024, 256, 0, stream>>>(ew1, nw1, nw2, wsw);
    wprep2<<<257, 256, 0, stream>>>(ew2, eb2, nw1, wsw);

    hipFuncSetAttribute(reinterpret_cast<const void*>(gnl_kernel),
                        hipFuncAttributeMaxDynamicSharedMemorySize, SMEM_BYTES);

    gnl_kernel<<<BSZ * TILES, 512, SMEM_BYTES, stream>>>(
        h, mask, eb1, nb1, nb2, wsw, out);
}

// Round 14
// 146.623 us; speedup vs baseline: 1.4454x; 1.0888x over previous
//
#include <hip/hip_runtime.h>
#include <hip/hip_bf16.h>

typedef __bf16 bf16_t;
typedef bf16_t bf16x8 __attribute__((ext_vector_type(8)));
typedef bf16_t bf16x4 __attribute__((ext_vector_type(4)));
typedef float f32x4 __attribute__((ext_vector_type(4)));

#define SEQ 4096
#define BSZ 32
#define T_TOK 96
#define TILES 43          // ceil(4096/96); last tile has 64 valid tokens
#define PROWS 98          // X panel rows: tokens t0-1 .. t0+96
#define LSTR 264          // row stride elems (528 B)
#define NPANEL (PROWS * LSTR)

// LDS: THREE 98x264 bf16 panels = 155232 B -> 1 block/CU.
//   X: h bf16, alive to P4 (residual + P3' fused K-half).
//   A: P1a out -> HN (P3' out).
//   B: P1a out -> S (overwritten after in-register S compute).
// Rationale (R13/R4 post-mortem): occupancy chase abandoned — co-resident
// blocks contend for the same LDS/L2 pipes. Instead amortize the 640 KB/block
// L2 weight stream over 2x the tokens.
#define OFF_X 0
#define OFF_A NPANEL
#define OFF_B (2 * NPANEL)
#define SMEM_ELEMS (3 * NPANEL)
#define SMEM_BYTES (SMEM_ELEMS * 2)     // 155232

// frag-linear weight bases (bf16 elems). Frag (nt,ks) = 512 elems;
// lane l (r=l&15,kg=l>>4), elem e -> W^T[nt*16+r][ks*32+kg*8+e]
#define W1F 0           // [w1a|w1b]: 32 nt
#define NAF 131072      // nw1a: 16 nt
#define WBF 196608      // W2B = ew2 @ nw1b: 16 nt
#define N2F 262144      // nw2: 16 nt
#define B2N 327680      // 256 f32: eb2 @ nw1b

#define BAR() asm volatile("s_waitcnt lgkmcnt(0)\n\ts_barrier" ::: "memory")

// ---- prepass 1: direct transposes -> frag-linear bf16 ----
__global__ void wprep(const float* __restrict__ ew1, const float* __restrict__ nw1,
                      const float* __restrict__ nw2, bf16_t* __restrict__ wsw) {
    int idx = blockIdx.x * 256 + threadIdx.x;      // 0..262143
    int region, rel, outbase;
    if (idx < 131072)      { region = 0; rel = idx;          outbase = W1F; }
    else if (idx < 196608) { region = 1; rel = idx - 131072; outbase = NAF; }
    else                   { region = 2; rel = idx - 196608; outbase = N2F; }
    int f = rel >> 9, o = rel & 511;
    int l = o >> 3, e = o & 7;
    int r = l & 15, kg = l >> 4;
    int nt = f >> 3, ks = f & 7;
    int k = ks * 32 + kg * 8 + e;
    int n = nt * 16 + r;
    float v;
    if (region == 0)
        v = (nt < 16) ? ew1[k * 256 + n] : ew1[(256 + k) * 256 + (n - 256)];
    else if (region == 1)
        v = nw1[k * 256 + n];
    else
        v = nw2[k * 256 + n];
    wsw[outbase + rel] = (bf16_t)v;
}

// ---- prepass 2: W2B = ew2 @ nw1b (frag-linear), b2n = eb2 @ nw1b ----
__global__ void wprep2(const float* __restrict__ ew2, const float* __restrict__ eb2,
                       const float* __restrict__ nw1, bf16_t* __restrict__ wsw) {
    int k = blockIdx.x;
    int n = threadIdx.x;
    if (k < 256) {
        float acc = 0.f;
        for (int j = 0; j < 256; ++j)
            acc += ew2[k * 256 + j] * nw1[(256 + j) * 256 + n];
        int ks = k >> 5, kg = (k >> 3) & 3, e = k & 7;
        int nt = n >> 4, r = n & 15;
        wsw[WBF + ((nt * 8 + ks) << 9) + ((kg * 16 + r) << 3) + e] = (bf16_t)acc;
    } else {
        float acc = 0.f;
        for (int j = 0; j < 256; ++j)
            acc += eb2[j] * nw1[(256 + j) * 256 + n];
        ((float*)(wsw + B2N))[n] = acc;
    }
}

// 512 threads, demand target < 128 VGPR (toolchain pin). P1b is FUSED into
// P3' (HN = relu(X@nw1a + S@W2B + ...)) so no f32 accumulators persist
// across phases — that's what makes T=96 fit the register budget.
__launch_bounds__(512, 2)
__global__ void gnl_kernel(const float* __restrict__ h, const float* __restrict__ mask,
                           const float* __restrict__ eb1, const float* __restrict__ nb1,
                           const float* __restrict__ nb2,
                           const bf16_t* __restrict__ wsw, float* __restrict__ out) {
    extern __shared__ bf16_t sm[];

    const int tid   = threadIdx.x;
    const int lane  = tid & 63;
    const int w     = tid >> 6;            // wave 0..7
    const int batch = blockIdx.x / TILES;
    const int tile  = blockIdx.x % TILES;
    const int t0    = tile * T_TOK;
    const long baseTok = (long)batch * SEQ;

    const int c   = lane & 15;             // token col / weight row
    const int kg  = lane >> 4;
    const int crb = kg << 2;               // C feature base {0,4,8,12}
    const int n0a = w * 16;
    const int n0b = (w + 8) * 16;

    auto loadw = [&](bf16x8 (&f)[8], int base, int nt) {
#pragma unroll
        for (int ks = 0; ks < 8; ++ks)
            f[ks] = *(const bf16x8*)(wsw + base + ((nt * 8 + ks) << 9) + (lane << 3));
    };
    auto loada = [&](bf16x8 (&f)[8], int poff, int rbase) {
        const bf16_t* p = sm + poff + (rbase + c) * LSTR + (kg << 3);
#pragma unroll
        for (int ks = 0; ks < 8; ++ks) f[ks] = *(const bf16x8*)(p + (ks << 5));
    };
    auto mfma2 = [&](bf16x8 (&f)[8], bf16x8 (&wa)[8], bf16x8 (&wb)[8],
                     f32x4& a0, f32x4& a1) {
        __builtin_amdgcn_s_setprio(1);
#pragma unroll
        for (int ks = 0; ks < 8; ++ks) {
            a0 = __builtin_amdgcn_mfma_f32_16x16x32_bf16(wa[ks], f[ks], a0, 0, 0, 0);
            a1 = __builtin_amdgcn_mfma_f32_16x16x32_bf16(wb[ks], f[ks], a1, 0, 0, 0);
        }
        __builtin_amdgcn_s_setprio(0);
    };

    // ---- prefetch P1a p=0 weight pair DURING stage (low-pressure region) ----
    bf16x8 wa0[8], wb0[8];
    loadw(wa0, W1F, w);
    loadw(wb0, W1F, w + 8);

    // ---------- stage h -> X (bf16, zero-padded boundary rows) ----------
#pragma unroll
    for (int it = 0; it < 7; ++it) {
        int cc = tid + it * 512;               // 98*32 = 3136 chunks
        if (cc < PROWS * 32) {
            int r = cc >> 5;
            int fc = (cc & 31) << 3;
            int t = t0 - 1 + r;
            bf16x8 v;
            if (t >= 0 && t < SEQ) {
                const float* src = h + (((long)(baseTok + t)) << 8) + fc;
                float4 x0 = ((const float4*)src)[0];
                float4 x1 = ((const float4*)src)[1];
                v[0] = (bf16_t)x0.x; v[1] = (bf16_t)x0.y;
                v[2] = (bf16_t)x0.z; v[3] = (bf16_t)x0.w;
                v[4] = (bf16_t)x1.x; v[5] = (bf16_t)x1.y;
                v[6] = (bf16_t)x1.z; v[7] = (bf16_t)x1.w;
            } else {
#pragma unroll
                for (int q = 0; q < 8; ++q) v[q] = (bf16_t)0.0f;
            }
            *(bf16x8*)(sm + OFF_X + r * LSTR + fc) = v;
        }
    }
    BAR();

    // ---------- Phase 1a: A,B panels = X @ [w1a|w1b] ----------
    // 7 m-tiles cover rows 0..111 (valid 0..97; mt=6 spill-reads land in the
    // A panel region — garbage inputs, outputs masked by row<PROWS).
#pragma unroll
    for (int p = 0; p < 2; ++p) {
        bf16x8 wa[8], wb[8];
        if (p == 0) {
#pragma unroll
            for (int ks = 0; ks < 8; ++ks) { wa[ks] = wa0[ks]; wb[ks] = wb0[ks]; }
        } else {
            loadw(wa, W1F, w + 16);
            loadw(wb, W1F, w + 24);
        }
        int poff = p ? OFF_B : OFF_A;
        bf16x8 fA[8], fB[8];
        loada(fA, OFF_X, 0);
#pragma unroll
        for (int mt = 0; mt < 7; ++mt) {
            bf16x8 (&cur)[8] = (mt & 1) ? fB : fA;
            bf16x8 (&nxt)[8] = (mt & 1) ? fA : fB;
            if (mt < 6) loada(nxt, OFF_X, (mt + 1) * 16);
            f32x4 aA = {0.f, 0.f, 0.f, 0.f}, aB = {0.f, 0.f, 0.f, 0.f};
            mfma2(cur, wa, wb, aA, aB);
            int row = mt * 16 + c;
            if (row < PROWS) {
                bf16x4 pA, pB;
#pragma unroll
                for (int q = 0; q < 4; ++q) { pA[q] = (bf16_t)aA[q]; pB[q] = (bf16_t)aB[q]; }
                *(bf16x4*)(sm + poff + row * LSTR + n0a + crb) = pA;
                *(bf16x4*)(sm + poff + row * LSTR + n0b + crb) = pB;
            }
        }
    }

    // prefetch ALL P3' weight sets (nw1a + W2B) — in flight across barriers
    bf16x8 na[8], nb8[8], wba[8], wbb[8];
    loadw(na, NAF, w);
    loadw(nb8, NAF, w + 8);
    loadw(wba, WBF, w);
    loadw(wbb, WBF, w + 8);
    BAR();

    // ---------- S pass (register-held; S overwrites B panel) ----------
    // S[i] = bl*relu(A[i]+B[i+1]+b1) + br*relu(A[i+2]+B[i+1]+b1), i = 0..95.
    bf16x8 svr[6];
#pragma unroll
    for (int it = 0; it < 6; ++it) {
        int cc = tid + it * 512;               // 96*32 = 3072 = 6*512 exact
        int i = cc >> 5;
        int fc = (cc & 31) << 3;
        float bl = (t0 + i >= 1) ? 1.f : 0.f;
        float br = (t0 + i <= SEQ - 2) ? 1.f : 0.f;
        bf16x8 aL = *(const bf16x8*)(sm + OFF_A + i * LSTR + fc);
        bf16x8 aR = *(const bf16x8*)(sm + OFF_A + (i + 2) * LSTR + fc);
        bf16x8 bC = *(const bf16x8*)(sm + OFF_B + (i + 1) * LSTR + fc);
        float4 b1a = *(const float4*)(eb1 + fc);
        float4 b1b = *(const float4*)(eb1 + fc + 4);
        bf16x8 sv;
#pragma unroll
        for (int q = 0; q < 8; ++q) {
            float b1f = (q < 4) ? ((const float*)&b1a)[q] : ((const float*)&b1b)[q - 4];
            float x = (float)bC[q] + b1f;
            float l = fmaxf((float)aL[q] + x, 0.f) * bl;
            float r = fmaxf((float)aR[q] + x, 0.f) * br;
            sv[q] = (bf16_t)(l + r);
        }
        svr[it] = sv;
    }
    BAR();   // all B reads done -> safe to overwrite B with S
#pragma unroll
    for (int it = 0; it < 6; ++it) {
        int cc = tid + it * 512;
        int i = cc >> 5;
        int fc = (cc & 31) << 3;
        *(bf16x8*)(sm + OFF_B + i * LSTR + fc) = svr[it];
    }
    BAR();

    // ---------- Phase 3' (fused K=512): HN = relu(X@nw1a + S@W2B + nb1 + cnt*b2n) ----------
    {
        float4 n1a = *(const float4*)(nb1 + n0a + crb);
        float4 n1b = *(const float4*)(nb1 + n0b + crb);
        const float* b2n = (const float*)(wsw + B2N);
        float4 c2a = *(const float4*)(b2n + n0a + crb);
        float4 c2b = *(const float4*)(b2n + n0b + crb);
        bf16x8 fX[8], fS[8];
#pragma unroll
        for (int tm = 0; tm < 6; ++tm) {
            loada(fX, OFF_X, 1 + tm * 16);     // token rows (X row = tok+1)
            loada(fS, OFF_B, tm * 16);         // S rows (= token index)
            f32x4 a0 = {0.f, 0.f, 0.f, 0.f}, a1 = {0.f, 0.f, 0.f, 0.f};
            mfma2(fX, na, nb8, a0, a1);
            mfma2(fS, wba, wbb, a0, a1);
            int row = tm * 16 + c;
            int t = t0 + row;
            float cnt = ((t >= 1) ? 1.f : 0.f) + ((t <= SEQ - 2) ? 1.f : 0.f);
            bf16x4 p0, p1;
#pragma unroll
            for (int q = 0; q < 4; ++q) {
                p0[q] = (bf16_t)fmaxf(a0[q] + ((const float*)&n1a)[q] + cnt * ((const float*)&c2a)[q], 0.f);
                p1[q] = (bf16_t)fmaxf(a1[q] + ((const float*)&n1b)[q] + cnt * ((const float*)&c2b)[q], 0.f);
            }
            *(bf16x4*)(sm + OFF_A + row * LSTR + n0a + crb) = p0;
            *(bf16x4*)(sm + OFF_A + row * LSTR + n0b + crb) = p1;
        }
    }
    // prefetch P4 weights (nw2) — na..wbb dead, register peak bounded
    bf16x8 n2a[8], n2b[8];
    loadw(n2a, N2F, w);
    loadw(n2b, N2F, w + 8);
    BAR();

    // ---------- Phase 4: out = X + mask * (HN @ nw2 + nb2) ----------
    {
        float4 v2a = *(const float4*)(nb2 + n0a + crb);
        float4 v2b = *(const float4*)(nb2 + n0b + crb);
        bf16x8 fA[8], fB[8];
        loada(fA, OFF_A, 0);
#pragma unroll
        for (int tm = 0; tm < 6; ++tm) {
            int row = tm * 16 + c;
            int tok = t0 + row;                   // >= SEQ only in last tile
            int tokc = (tok < SEQ) ? tok : (SEQ - 1);
            long t = baseTok + tokc;
            float m = mask[t];                    // clamped, issued early
            bf16x8 (&cur)[8] = (tm & 1) ? fB : fA;
            bf16x8 (&nxt)[8] = (tm & 1) ? fA : fB;
            if (tm < 5) loada(nxt, OFF_A, (tm + 1) * 16);
            f32x4 a0 = {0.f, 0.f, 0.f, 0.f}, a1 = {0.f, 0.f, 0.f, 0.f};
            mfma2(cur, n2a, n2b, a0, a1);
            int rrow = row + 1;                   // X row of this token
            bf16x4 r0 = *(const bf16x4*)(sm + OFF_X + rrow * LSTR + n0a + crb);
            bf16x4 r1 = *(const bf16x4*)(sm + OFF_X + rrow * LSTR + n0b + crb);
            if (tok < SEQ) {
                long g0 = (t << 8) + n0a + crb;
                long g1 = (t << 8) + n0b + crb;
                float4 o0, o1;
                o0.x = (float)r0[0] + m * (a0[0] + v2a.x);
                o0.y = (float)r0[1] + m * (a0[1] + v2a.y);
                o0.z = (float)r0[2] + m * (a0[2] + v2a.z);
                o0.w = (float)r0[3] + m * (a0[3] + v2a.w);
                o1.x = (float)r1[0] + m * (a1[0] + v2b.x);
                o1.y = (float)r1[1] + m * (a1[1] + v2b.y);
                o1.z = (float)r1[2] + m * (a1[2] + v2b.z);
                o1.w = (float)r1[3] + m * (a1[3] + v2b.w);
                *(float4*)(out + g0) = o0;
                *(float4*)(out + g1) = o1;
            }
        }
    }
}

extern "C" void kernel_launch(void* const* d_in, const int* in_sizes, int n_in,
                              void* d_out, int out_size, void* d_ws, size_t ws_size,
                              hipStream_t stream) {
    const float* h    = (const float*)d_in[0];
    const float* mask = (const float*)d_in[1];
    const float* ew1  = (const float*)d_in[2];
    const float* eb1  = (const float*)d_in[3];
    const float* ew2  = (const float*)d_in[4];
    const float* eb2  = (const float*)d_in[5];
    const float* nw1  = (const float*)d_in[6];
    const float* nb1  = (const float*)d_in[7];
    const float* nw2  = (const float*)d_in[8];
    const float* nb2  = (const float*)d_in[9];
    float* out   = (float*)d_out;
    bf16_t* wsw  = (bf16_t*)d_ws;

    wprep<<<1024, 256, 0, stream>>>(ew1, nw1, nw2, wsw);
    wprep2<<<257, 256, 0, stream>>>(ew2, eb2, nw1, wsw);

    hipFuncSetAttribute(reinterpret_cast<const void*>(gnl_kernel),
                        hipFuncAttributeMaxDynamicSharedMemorySize, SMEM_BYTES);

    gnl_kernel<<<BSZ * TILES, 512, SMEM_BYTES, stream>>>(
        h, mask, eb1, nb1, nb2, wsw, out);
}